// Round 1
// 1157.626 us; speedup vs baseline: 1.1021x; 1.1021x over previous
//
#include <hip/hip_runtime.h>

typedef __attribute__((ext_vector_type(8))) __bf16 bf16x8;
typedef __attribute__((ext_vector_type(4))) __bf16 bf16x4;
typedef __attribute__((ext_vector_type(4))) float floatx4;

#define B_DIM 2
#define S_DIM 2048
#define NH    32
#define NKV   8
#define HD    128
#define HID   4096

// ---------------------------------------------------------------- helpers
__device__ __forceinline__ void gload_lds16(const void* gsrc, void* ldst) {
  __builtin_amdgcn_global_load_lds(
      (__attribute__((address_space(1))) unsigned int*)(void*)gsrc,
      (__attribute__((address_space(3))) unsigned int*)ldst, 16, 0, 0);
}

// ---------------------------------------------------------------- fp32 -> bf16
__global__ void f2bf_kernel(const float* __restrict__ in, __bf16* __restrict__ out, int n) {
  int i = (blockIdx.x * 256 + threadIdx.x) * 4;
  if (i >= n) return;
  float4 v = *(const float4*)(in + i);
  bf16x4 o;
  o.x = (__bf16)v.x; o.y = (__bf16)v.y; o.z = (__bf16)v.z; o.w = (__bf16)v.w;
  *(bf16x4*)(out + i) = o;
}

// ---------------------------------------------------------------- GEMM C = A * B^T
// A [M][K] bf16 row-major, Bw [N][K] bf16 row-major.
// MODE 0: store bf16 permuted to Q layout [B,32,S,D]
// MODE 1: store bf16 permuted to K layout [B,8,S,D]
// MODE 2: store bf16 permuted to Vt layout [B,8,D,S]
// MODE 3: store fp32 plain row-major [M][N]
template <int MODE>
__global__ __launch_bounds__(256)
void gemm_bt(const __bf16* __restrict__ A, const __bf16* __restrict__ Bw,
             void* __restrict__ Cout, int M, int N, int K) {
  __shared__ uint4 smem4[1024];            // 16 KB: As 8 KB + Bs 8 KB
  char* smem = (char*)smem4;
  char* As = smem;                          // [128 rows][32 k] bf16
  char* Bs = smem + 8192;
  const int tid = threadIdx.x;
  const int lane = tid & 63, wave = tid >> 6;
  const int quad = lane >> 4, l16 = lane & 15;
  const int bm0 = blockIdx.y * 128, bn0 = blockIdx.x * 128;
  const __bf16* Ag = A + (size_t)bm0 * K;
  const __bf16* Bg = Bw + (size_t)bn0 * K;
  const int wm = (wave >> 1) * 64, wn = (wave & 1) * 64;

  floatx4 acc[4][4] = {};

  for (int k0 = 0; k0 < K; k0 += 32) {
    __syncthreads();
    {
      int slot = tid;
      gload_lds16(Ag + (slot >> 2) * K + k0 + (slot & 3) * 8, As + slot * 16);
      gload_lds16(Bg + (slot >> 2) * K + k0 + (slot & 3) * 8, Bs + slot * 16);
      slot = tid + 256;
      gload_lds16(Ag + (slot >> 2) * K + k0 + (slot & 3) * 8, As + slot * 16);
      gload_lds16(Bg + (slot >> 2) * K + k0 + (slot & 3) * 8, Bs + slot * 16);
    }
    __syncthreads();
    bf16x8 af[4], bfr[4];
#pragma unroll
    for (int i = 0; i < 4; i++)
      af[i] = *(const bf16x8*)(As + (wm + i * 16 + l16) * 64 + quad * 16);
#pragma unroll
    for (int i = 0; i < 4; i++)
      bfr[i] = *(const bf16x8*)(Bs + (wn + i * 16 + l16) * 64 + quad * 16);
#pragma unroll
    for (int mi = 0; mi < 4; mi++)
#pragma unroll
      for (int ni = 0; ni < 4; ni++)
        acc[mi][ni] = __builtin_amdgcn_mfma_f32_16x16x32_bf16(af[mi], bfr[ni], acc[mi][ni], 0, 0, 0);
  }

#pragma unroll
  for (int mi = 0; mi < 4; mi++)
#pragma unroll
    for (int ni = 0; ni < 4; ni++)
#pragma unroll
      for (int r = 0; r < 4; r++) {
        int row = bm0 + wm + mi * 16 + quad * 4 + r;   // m index (= b*2048+s)
        int col = bn0 + wn + ni * 16 + l16;            // n index
        float v = acc[mi][ni][r];
        if (MODE == 3) {
          ((float*)Cout)[(size_t)row * N + col] = v;
        } else {
          int b = row >> 11, s = row & 2047;
          int h = col >> 7, d = col & 127;
          size_t idx;
          if (MODE == 0)      idx = ((size_t)(b * NH + h) * S_DIM + s) * HD + d;
          else if (MODE == 1) idx = ((size_t)(b * NKV + h) * S_DIM + s) * HD + d;
          else                idx = ((size_t)(b * NKV + h) * HD + d) * S_DIM + s;
          ((__bf16*)Cout)[idx] = (__bf16)v;
        }
      }
}

// ---------------------------------------------------------------- RoPE (in place)
// x layout [B, nh, S, D]; pairs (j, j+64) rotated. lognh = log2(nh).
__global__ void rope_kernel(__bf16* __restrict__ x, const int* __restrict__ pos, int lognh) {
  int t = blockIdx.x * 256 + threadIdx.x;
  int j = t & 63;
  int s = (t >> 6) & (S_DIM - 1);
  int bh = t >> 17;
  int b = bh >> lognh;
  float p = (float)pos[b * S_DIM + s];
  float invf = exp2f((float)j * (-13.2877123795494f / 64.0f));
  float ang = p * invf;
  float sn, cs;
  sincosf(ang, &sn, &cs);
  size_t base = ((size_t)bh * S_DIM + s) * HD;
  float x1 = (float)x[base + j];
  float x2 = (float)x[base + j + 64];
  x[base + j]      = (__bf16)(x1 * cs - x2 * sn);
  x[base + j + 64] = (__bf16)(x2 * cs + x1 * sn);
}

// ---------------------------------------------------------------- flash attention
// Q [B,32,S,D], K [B,8,S,D], Vt [B,8,D,S] bf16 -> O [B,S,32*128] bf16.
// Block: 256 thr (4 waves), Q-tile 64 (16 q-rows/wave), K-tile 64, causal.
// Q held in registers. K/V double-buffered in LDS, staged async via
// global_load_lds (linear LDS dest, pre-swizzled global source), counted vmcnt.
// LDS 72 KB: K dbuf 2x16K (XOR-15 swz) | V dbuf 2x16K (XOR-7) | Ps 8K (XOR-7)
__device__ __forceinline__ void stage_kv(const __bf16* __restrict__ Kg,
                                         const __bf16* __restrict__ Vg,
                                         char* Kb, char* Vb, int k0, int tid) {
#pragma unroll
  for (int i = 0; i < 4; i++) {
    int slot = i * 256 + tid;                       // 64 rows x 16 units
    int row = slot >> 4;
    int u = (slot & 15) ^ (row & 15);               // inverse-swizzled source
    gload_lds16(Kg + (size_t)(k0 + row) * HD + u * 8, Kb + slot * 16);
  }
#pragma unroll
  for (int i = 0; i < 4; i++) {
    int slot = i * 256 + tid;                       // 128 rows x 8 units
    int row = slot >> 3;
    int u = (slot & 7) ^ (row & 7);
    gload_lds16(Vg + (size_t)row * S_DIM + k0 + u * 8, Vb + slot * 16);
  }
}

__global__ __launch_bounds__(256, 2)
void attn_kernel(const __bf16* __restrict__ Q, const __bf16* __restrict__ K,
                 const __bf16* __restrict__ Vt, __bf16* __restrict__ O) {
  __shared__ uint4 smem4[4608];            // 73728 B
  char* smem = (char*)smem4;
  char* Ps = smem + 65536;
  const int tid = threadIdx.x;
  const int lane = tid & 63, wave = tid >> 6;
  const int quad = lane >> 4, l16 = lane & 15;
  const int qt = 31 - (int)blockIdx.x;     // longest blocks dispatched first
  const int h = blockIdx.y, b = blockIdx.z;
  const int q0 = qt * 64, kvh = h >> 2;
  const __bf16* Qg = Q + ((size_t)(b * NH + h) * S_DIM + q0) * HD;
  const __bf16* Kg = K + (size_t)(b * NKV + kvh) * S_DIM * HD;
  const __bf16* Vg = Vt + (size_t)(b * NKV + kvh) * HD * S_DIM;
  const int nkt = qt + 1;
  const float scale = 0.08838834764831845f;   // 1/sqrt(128)

  // Q fragments in registers (wave owns 16 q-rows)
  bf16x8 qf[4];
#pragma unroll
  for (int ks = 0; ks < 4; ks++)
    qf[ks] = *(const bf16x8*)(Qg + (wave * 16 + l16) * HD + (ks * 4 + quad) * 8);

  floatx4 oacc[8] = {};
  float mrow[4] = {-1e30f, -1e30f, -1e30f, -1e30f};
  float lrow[4] = {0.f, 0.f, 0.f, 0.f};

  // prologue: stage tile 0 into buffer 0
  stage_kv(Kg, Vg, smem, smem + 32768, 0, tid);

  for (int kt = 0; kt < nkt; kt++) {
    char* Kc = smem + (kt & 1) * 16384;
    char* Vc = smem + 32768 + (kt & 1) * 16384;
    const int k0 = kt * 64;

    if (kt + 1 < nkt) {
      // issue next tile's 8 DMA loads into the other buffer, then wait for
      // current tile's 8 (counted vmcnt — next tile's loads stay in flight)
      stage_kv(Kg, Vg, smem + ((kt + 1) & 1) * 16384,
               smem + 32768 + ((kt + 1) & 1) * 16384, k0 + 64, tid);
      asm volatile("s_waitcnt vmcnt(8)" ::: "memory");
    } else {
      asm volatile("s_waitcnt vmcnt(0)" ::: "memory");
    }
    __builtin_amdgcn_s_barrier();            // tile kt data visible to all waves
    asm volatile("" ::: "memory");

    // ---- S = Q K^T
    floatx4 sacc[4] = {};
#pragma unroll
    for (int ks = 0; ks < 4; ks++) {
      bf16x8 bk[4];
#pragma unroll
      for (int n = 0; n < 4; n++) {
        int row = n * 16 + l16;
        bk[n] = *(const bf16x8*)(Kc + row * 256 + (((ks * 4 + quad) ^ (row & 15)) << 4));
      }
#pragma unroll
      for (int n = 0; n < 4; n++)
        sacc[n] = __builtin_amdgcn_mfma_f32_16x16x32_bf16(qf[ks], bk[n], sacc[n], 0, 0, 0);
    }

    // ---- online softmax (rows wave-private)
    const bool maskt = (kt == nkt - 1);      // only the diagonal tile
    float pm[4][4];
    float rmax[4] = {-3e30f, -3e30f, -3e30f, -3e30f};
#pragma unroll
    for (int n = 0; n < 4; n++)
#pragma unroll
      for (int r = 0; r < 4; r++) {
        float sv = sacc[n][r] * scale;
        if (maskt) {
          int qrow = q0 + wave * 16 + quad * 4 + r;
          int kcol = k0 + n * 16 + l16;
          if (kcol > qrow) sv = -1e30f;
        }
        pm[n][r] = sv;
        rmax[r] = fmaxf(rmax[r], sv);
      }
#pragma unroll
    for (int r = 0; r < 4; r++) {
      float v = rmax[r];
      v = fmaxf(v, __shfl_xor(v, 1));
      v = fmaxf(v, __shfl_xor(v, 2));
      v = fmaxf(v, __shfl_xor(v, 4));
      v = fmaxf(v, __shfl_xor(v, 8));
      float nm = fmaxf(mrow[r], v);
      float al = __expf(mrow[r] - nm);
      mrow[r] = nm;
      float rs = 0.f;
#pragma unroll
      for (int n = 0; n < 4; n++) {
        float p = __expf(pm[n][r] - nm);
        pm[n][r] = p;
        rs += p;
      }
      rs += __shfl_xor(rs, 1);
      rs += __shfl_xor(rs, 2);
      rs += __shfl_xor(rs, 4);
      rs += __shfl_xor(rs, 8);
      lrow[r] = lrow[r] * al + rs;
#pragma unroll
      for (int n = 0; n < 8; n++) oacc[n][r] *= al;
    }
    // write P (bf16) to LDS — wave-private rows, no barrier needed
#pragma unroll
    for (int n = 0; n < 4; n++)
#pragma unroll
      for (int r = 0; r < 4; r++) {
        int row = wave * 16 + quad * 4 + r;
        int col = n * 16 + l16;
        *(__bf16*)(Ps + row * 128 + (((col >> 3) ^ (row & 7)) << 4) + (col & 7) * 2) =
            (__bf16)pm[n][r];
      }
    asm volatile("s_waitcnt lgkmcnt(0)" ::: "memory");   // P writes landed

    // ---- O += P V
#pragma unroll
    for (int ks = 0; ks < 2; ks++) {
      int prow = wave * 16 + l16;
      bf16x8 ap = *(const bf16x8*)(Ps + prow * 128 + (((ks * 4 + quad) ^ (prow & 7)) << 4));
#pragma unroll
      for (int n = 0; n < 8; n++) {
        int vrow = n * 16 + l16;
        bf16x8 bv = *(const bf16x8*)(Vc + vrow * 128 + (((ks * 4 + quad) ^ (vrow & 7)) << 4));
        oacc[n] = __builtin_amdgcn_mfma_f32_16x16x32_bf16(ap, bv, oacc[n], 0, 0, 0);
      }
    }

    asm volatile("" ::: "memory");
    __builtin_amdgcn_s_barrier();            // buffers free for next prefetch
    asm volatile("" ::: "memory");
  }

  // epilogue: O /= l, store to [B,S,H*D]
#pragma unroll
  for (int n = 0; n < 8; n++)
#pragma unroll
    for (int r = 0; r < 4; r++) {
      int row = wave * 16 + quad * 4 + r;
      int col = n * 16 + l16;
      float v = oacc[n][r] / lrow[r];
      O[(size_t)(b * S_DIM + q0 + row) * HID + h * HD + col] = (__bf16)v;
    }
}

// ---------------------------------------------------------------- launch
extern "C" void kernel_launch(void* const* d_in, const int* in_sizes, int n_in,
                              void* d_out, int out_size, void* d_ws, size_t ws_size,
                              hipStream_t stream) {
  const float* hs = (const float*)d_in[0];
  const float* wq = (const float*)d_in[1];
  const float* wk = (const float*)d_in[2];
  const float* wv = (const float*)d_in[3];
  const float* wo = (const float*)d_in[4];
  // d_in[5] = attention_mask (pure causal; implemented directly)
  const int* pos = (const int*)d_in[6];

  char* ws = (char*)d_ws;
  __bf16* Xb  = (__bf16*)(ws);                 // 33.55 MB  [4096][4096]
  __bf16* Wqb = (__bf16*)(ws + 33554432);      // 33.55 MB
  __bf16* Wkb = (__bf16*)(ws + 67108864);      //  8.39 MB
  __bf16* Wvb = (__bf16*)(ws + 75497472);      //  8.39 MB
  __bf16* Wob = (__bf16*)(ws + 83886080);      // 33.55 MB
  __bf16* Qb  = (__bf16*)(ws + 117440512);     // 33.55 MB  [B,32,S,D]
  __bf16* Kb  = (__bf16*)(ws + 150994944);     //  8.39 MB  [B,8,S,D]
  __bf16* Vtb = (__bf16*)(ws + 159383552);     //  8.39 MB  [B,8,D,S]
  __bf16* Ab  = (__bf16*)(ws + 167772160);     // 33.55 MB  attn out [4096][4096]
  if (ws_size < 201326592u) return;

  const int M = B_DIM * S_DIM;  // 4096

  f2bf_kernel<<<16384, 256, 0, stream>>>(hs, Xb, 16777216);
  f2bf_kernel<<<16384, 256, 0, stream>>>(wq, Wqb, 16777216);
  f2bf_kernel<<<4096, 256, 0, stream>>>(wk, Wkb, 4194304);
  f2bf_kernel<<<4096, 256, 0, stream>>>(wv, Wvb, 4194304);
  f2bf_kernel<<<16384, 256, 0, stream>>>(wo, Wob, 16777216);

  gemm_bt<0><<<dim3(32, 32), 256, 0, stream>>>(Xb, Wqb, Qb, M, 4096, 4096);
  gemm_bt<1><<<dim3(8, 32), 256, 0, stream>>>(Xb, Wkb, Kb, M, 1024, 4096);
  gemm_bt<2><<<dim3(8, 32), 256, 0, stream>>>(Xb, Wvb, Vtb, M, 1024, 4096);

  rope_kernel<<<32768, 256, 0, stream>>>(Qb, pos, 5);   // B*32*2048*64 / 256
  rope_kernel<<<8192, 256, 0, stream>>>(Kb, pos, 3);    // B*8*2048*64 / 256

  attn_kernel<<<dim3(32, 32, 2), 256, 0, stream>>>(Qb, Kb, Vtb, Ab);

  gemm_bt<3><<<dim3(32, 32), 256, 0, stream>>>(Ab, Wob, d_out, M, 4096, 4096);
}

// Round 2
// 1046.851 us; speedup vs baseline: 1.2188x; 1.1058x over previous
//
#include <hip/hip_runtime.h>

typedef __attribute__((ext_vector_type(8))) __bf16 bf16x8;
typedef __attribute__((ext_vector_type(4))) __bf16 bf16x4;
typedef __attribute__((ext_vector_type(4))) float floatx4;

#define B_DIM 2
#define S_DIM 2048
#define NH    32
#define NKV   8
#define HD    128
#define HID   4096

// ---------------------------------------------------------------- helpers
__device__ __forceinline__ void gload_lds16(const void* gsrc, void* ldst) {
  __builtin_amdgcn_global_load_lds(
      (__attribute__((address_space(1))) unsigned int*)(void*)gsrc,
      (__attribute__((address_space(3))) unsigned int*)ldst, 16, 0, 0);
}

// ---------------------------------------------------------------- fp32 -> bf16
__global__ void f2bf_kernel(const float* __restrict__ in, __bf16* __restrict__ out, int n) {
  int i = (blockIdx.x * 256 + threadIdx.x) * 4;
  if (i >= n) return;
  float4 v = *(const float4*)(in + i);
  bf16x4 o;
  o.x = (__bf16)v.x; o.y = (__bf16)v.y; o.z = (__bf16)v.z; o.w = (__bf16)v.w;
  *(bf16x4*)(out + i) = o;
}

// ---------------------------------------------------------------- GEMM C = A * B^T
// A [M][K] bf16 row-major, Bw [N][K] bf16 row-major.
// MODE 0: store bf16 permuted to Q layout [B,32,S,D]
// MODE 1: store bf16 permuted to K layout [B,8,S,D]
// MODE 2: store bf16 permuted to Vt layout [B,8,D,S]
// MODE 3: store fp32 plain row-major [M][N]
template <int MODE>
__global__ __launch_bounds__(256)
void gemm_bt(const __bf16* __restrict__ A, const __bf16* __restrict__ Bw,
             void* __restrict__ Cout, int M, int N, int K) {
  __shared__ uint4 smem4[1024];            // 16 KB: As 8 KB + Bs 8 KB
  char* smem = (char*)smem4;
  char* As = smem;                          // [128 rows][32 k] bf16
  char* Bs = smem + 8192;
  const int tid = threadIdx.x;
  const int lane = tid & 63, wave = tid >> 6;
  const int quad = lane >> 4, l16 = lane & 15;
  const int bm0 = blockIdx.y * 128, bn0 = blockIdx.x * 128;
  const __bf16* Ag = A + (size_t)bm0 * K;
  const __bf16* Bg = Bw + (size_t)bn0 * K;
  const int wm = (wave >> 1) * 64, wn = (wave & 1) * 64;

  floatx4 acc[4][4] = {};

  for (int k0 = 0; k0 < K; k0 += 32) {
    __syncthreads();
    {
      int slot = tid;
      gload_lds16(Ag + (slot >> 2) * K + k0 + (slot & 3) * 8, As + slot * 16);
      gload_lds16(Bg + (slot >> 2) * K + k0 + (slot & 3) * 8, Bs + slot * 16);
      slot = tid + 256;
      gload_lds16(Ag + (slot >> 2) * K + k0 + (slot & 3) * 8, As + slot * 16);
      gload_lds16(Bg + (slot >> 2) * K + k0 + (slot & 3) * 8, Bs + slot * 16);
    }
    __syncthreads();
    bf16x8 af[4], bfr[4];
#pragma unroll
    for (int i = 0; i < 4; i++)
      af[i] = *(const bf16x8*)(As + (wm + i * 16 + l16) * 64 + quad * 16);
#pragma unroll
    for (int i = 0; i < 4; i++)
      bfr[i] = *(const bf16x8*)(Bs + (wn + i * 16 + l16) * 64 + quad * 16);
#pragma unroll
    for (int mi = 0; mi < 4; mi++)
#pragma unroll
      for (int ni = 0; ni < 4; ni++)
        acc[mi][ni] = __builtin_amdgcn_mfma_f32_16x16x32_bf16(af[mi], bfr[ni], acc[mi][ni], 0, 0, 0);
  }

#pragma unroll
  for (int mi = 0; mi < 4; mi++)
#pragma unroll
    for (int ni = 0; ni < 4; ni++)
#pragma unroll
      for (int r = 0; r < 4; r++) {
        int row = bm0 + wm + mi * 16 + quad * 4 + r;   // m index (= b*2048+s)
        int col = bn0 + wn + ni * 16 + l16;            // n index
        float v = acc[mi][ni][r];
        if (MODE == 3) {
          ((float*)Cout)[(size_t)row * N + col] = v;
        } else {
          int b = row >> 11, s = row & 2047;
          int h = col >> 7, d = col & 127;
          size_t idx;
          if (MODE == 0)      idx = ((size_t)(b * NH + h) * S_DIM + s) * HD + d;
          else if (MODE == 1) idx = ((size_t)(b * NKV + h) * S_DIM + s) * HD + d;
          else                idx = ((size_t)(b * NKV + h) * HD + d) * S_DIM + s;
          ((__bf16*)Cout)[idx] = (__bf16)v;
        }
      }
}

// ---------------------------------------------------------------- RoPE (in place)
// x layout [B, nh, S, D]; pairs (j, j+64) rotated. lognh = log2(nh).
__global__ void rope_kernel(__bf16* __restrict__ x, const int* __restrict__ pos, int lognh) {
  int t = blockIdx.x * 256 + threadIdx.x;
  int j = t & 63;
  int s = (t >> 6) & (S_DIM - 1);
  int bh = t >> 17;
  int b = bh >> lognh;
  float p = (float)pos[b * S_DIM + s];
  float invf = exp2f((float)j * (-13.2877123795494f / 64.0f));
  float ang = p * invf;
  float sn, cs;
  sincosf(ang, &sn, &cs);
  size_t base = ((size_t)bh * S_DIM + s) * HD;
  float x1 = (float)x[base + j];
  float x2 = (float)x[base + j + 64];
  x[base + j]      = (__bf16)(x1 * cs - x2 * sn);
  x[base + j + 64] = (__bf16)(x2 * cs + x1 * sn);
}

// ---------------------------------------------------------------- flash attention
// Q [B,32,S,D], K [B,8,S,D], Vt [B,8,D,S] bf16 -> O [B,S,32*128] bf16.
// Block: 512 thr (8 waves), Q-tile 128 (16 q-rows/wave), K-tile 64, causal.
// Each block processes TWO complementary Q-tiles (qt, 15-qt) -> every block
// does exactly 34 K-tiles: perfect static balance, grid = 512 = 2 blocks/CU
// fully resident (no dispatch rounds).
// Q held in registers. K/V double-buffered in LDS, staged async via
// global_load_lds (linear LDS dest, pre-swizzled global source), counted vmcnt.
// LDS 80 KB: K dbuf 2x16K (XOR-15 swz) | V dbuf 2x16K (XOR-7) | Ps 16K (XOR-7)
__device__ __forceinline__ void stage_kv(const __bf16* __restrict__ Kg,
                                         const __bf16* __restrict__ Vg,
                                         char* Kb, char* Vb, int k0, int tid) {
#pragma unroll
  for (int i = 0; i < 2; i++) {
    int slot = i * 512 + tid;                       // 64 rows x 16 units
    int row = slot >> 4;
    int u = (slot & 15) ^ (row & 15);               // inverse-swizzled source
    gload_lds16(Kg + (size_t)(k0 + row) * HD + u * 8, Kb + slot * 16);
  }
#pragma unroll
  for (int i = 0; i < 2; i++) {
    int slot = i * 512 + tid;                       // 128 rows x 8 units
    int row = slot >> 3;
    int u = (slot & 7) ^ (row & 7);
    gload_lds16(Vg + (size_t)row * S_DIM + k0 + u * 8, Vb + slot * 16);
  }
}

__global__ __launch_bounds__(512, 4)
void attn_kernel(const __bf16* __restrict__ Q, const __bf16* __restrict__ K,
                 const __bf16* __restrict__ Vt, __bf16* __restrict__ O) {
  __shared__ uint4 smem4[5120];            // 81920 B
  char* smem = (char*)smem4;
  char* Ps = smem + 65536;                 // 128 rows x 128 B
  const int tid = threadIdx.x;
  const int lane = tid & 63, wave = tid >> 6;
  const int quad = lane >> 4, l16 = lane & 15;
  const int h = blockIdx.y, b = blockIdx.z;
  const int kvh = h >> 2;
  const __bf16* Kg = K + (size_t)(b * NKV + kvh) * S_DIM * HD;
  const __bf16* Vg = Vt + (size_t)(b * NKV + kvh) * HD * S_DIM;
  const float scale = 0.08838834764831845f;   // 1/sqrt(128)

  for (int pass = 0; pass < 2; ++pass) {
    const int qt = pass ? (15 - (int)blockIdx.x) : (int)blockIdx.x;
    const int q0 = qt * 128;
    const __bf16* Qg = Q + ((size_t)(b * NH + h) * S_DIM + q0) * HD;
    const int nkt = qt * 2 + 2;

    // Q fragments in registers (wave owns 16 q-rows)
    bf16x8 qf[4];
#pragma unroll
    for (int ks = 0; ks < 4; ks++)
      qf[ks] = *(const bf16x8*)(Qg + (wave * 16 + l16) * HD + (ks * 4 + quad) * 8);

    floatx4 oacc[8] = {};
    float mrow[4] = {-1e30f, -1e30f, -1e30f, -1e30f};
    float lrow[4] = {0.f, 0.f, 0.f, 0.f};

    // prologue: stage tile 0 into buffer 0
    stage_kv(Kg, Vg, smem, smem + 32768, 0, tid);

    for (int kt = 0; kt < nkt; kt++) {
      char* Kc = smem + (kt & 1) * 16384;
      char* Vc = smem + 32768 + (kt & 1) * 16384;
      const int k0 = kt * 64;

      if (kt + 1 < nkt) {
        // issue next tile's 4 DMA loads/thread into the other buffer, then
        // wait only for the current tile's 4 (counted vmcnt)
        stage_kv(Kg, Vg, smem + ((kt + 1) & 1) * 16384,
                 smem + 32768 + ((kt + 1) & 1) * 16384, k0 + 64, tid);
        asm volatile("s_waitcnt vmcnt(4)" ::: "memory");
      } else {
        asm volatile("s_waitcnt vmcnt(0)" ::: "memory");
      }
      __builtin_amdgcn_s_barrier();            // tile kt data visible to all waves
      asm volatile("" ::: "memory");

      // ---- S = Q K^T
      floatx4 sacc[4] = {};
#pragma unroll
      for (int ks = 0; ks < 4; ks++) {
        bf16x8 bk[4];
#pragma unroll
        for (int n = 0; n < 4; n++) {
          int row = n * 16 + l16;
          bk[n] = *(const bf16x8*)(Kc + row * 256 + (((ks * 4 + quad) ^ (row & 15)) << 4));
        }
#pragma unroll
        for (int n = 0; n < 4; n++)
          sacc[n] = __builtin_amdgcn_mfma_f32_16x16x32_bf16(qf[ks], bk[n], sacc[n], 0, 0, 0);
      }

      // ---- online softmax (rows wave-private)
      const bool maskt = (kt >= nkt - 2);      // diagonal-crossing tiles
      float pm[4][4];
      float rmax[4] = {-3e30f, -3e30f, -3e30f, -3e30f};
#pragma unroll
      for (int n = 0; n < 4; n++)
#pragma unroll
        for (int r = 0; r < 4; r++) {
          float sv = sacc[n][r] * scale;
          if (maskt) {
            int qrow = q0 + wave * 16 + quad * 4 + r;
            int kcol = k0 + n * 16 + l16;
            if (kcol > qrow) sv = -1e30f;
          }
          pm[n][r] = sv;
          rmax[r] = fmaxf(rmax[r], sv);
        }
#pragma unroll
      for (int r = 0; r < 4; r++) {
        float v = rmax[r];
        v = fmaxf(v, __shfl_xor(v, 1));
        v = fmaxf(v, __shfl_xor(v, 2));
        v = fmaxf(v, __shfl_xor(v, 4));
        v = fmaxf(v, __shfl_xor(v, 8));
        float nm = fmaxf(mrow[r], v);
        float al = __expf(mrow[r] - nm);
        mrow[r] = nm;
        float rs = 0.f;
#pragma unroll
        for (int n = 0; n < 4; n++) {
          float p = __expf(pm[n][r] - nm);
          pm[n][r] = p;
          rs += p;
        }
        rs += __shfl_xor(rs, 1);
        rs += __shfl_xor(rs, 2);
        rs += __shfl_xor(rs, 4);
        rs += __shfl_xor(rs, 8);
        lrow[r] = lrow[r] * al + rs;
#pragma unroll
        for (int n = 0; n < 8; n++) oacc[n][r] *= al;
      }
      // write P (bf16) to LDS — wave-private rows, no barrier needed
#pragma unroll
      for (int n = 0; n < 4; n++)
#pragma unroll
        for (int r = 0; r < 4; r++) {
          int row = wave * 16 + quad * 4 + r;
          int col = n * 16 + l16;
          *(__bf16*)(Ps + row * 128 + (((col >> 3) ^ (row & 7)) << 4) + (col & 7) * 2) =
              (__bf16)pm[n][r];
        }
      asm volatile("s_waitcnt lgkmcnt(0)" ::: "memory");   // P writes landed

      // ---- O += P V
#pragma unroll
      for (int ks = 0; ks < 2; ks++) {
        int prow = wave * 16 + l16;
        bf16x8 ap = *(const bf16x8*)(Ps + prow * 128 + (((ks * 4 + quad) ^ (prow & 7)) << 4));
#pragma unroll
        for (int n = 0; n < 8; n++) {
          int vrow = n * 16 + l16;
          bf16x8 bv = *(const bf16x8*)(Vc + vrow * 128 + (((ks * 4 + quad) ^ (vrow & 7)) << 4));
          oacc[n] = __builtin_amdgcn_mfma_f32_16x16x32_bf16(ap, bv, oacc[n], 0, 0, 0);
        }
      }

      asm volatile("" ::: "memory");
      __builtin_amdgcn_s_barrier();            // buffers free for next prefetch
      asm volatile("" ::: "memory");
    }

    // epilogue: O /= l, store to [B,S,H*D]
#pragma unroll
    for (int n = 0; n < 8; n++)
#pragma unroll
      for (int r = 0; r < 4; r++) {
        int row = wave * 16 + quad * 4 + r;
        int col = n * 16 + l16;
        float v = oacc[n][r] / lrow[r];
        O[(size_t)(b * S_DIM + q0 + row) * HID + h * HD + col] = (__bf16)v;
      }
  }
}

// ---------------------------------------------------------------- launch
extern "C" void kernel_launch(void* const* d_in, const int* in_sizes, int n_in,
                              void* d_out, int out_size, void* d_ws, size_t ws_size,
                              hipStream_t stream) {
  const float* hs = (const float*)d_in[0];
  const float* wq = (const float*)d_in[1];
  const float* wk = (const float*)d_in[2];
  const float* wv = (const float*)d_in[3];
  const float* wo = (const float*)d_in[4];
  // d_in[5] = attention_mask (pure causal; implemented directly)
  const int* pos = (const int*)d_in[6];

  char* ws = (char*)d_ws;
  __bf16* Xb  = (__bf16*)(ws);                 // 33.55 MB  [4096][4096]
  __bf16* Wqb = (__bf16*)(ws + 33554432);      // 33.55 MB
  __bf16* Wkb = (__bf16*)(ws + 67108864);      //  8.39 MB
  __bf16* Wvb = (__bf16*)(ws + 75497472);      //  8.39 MB
  __bf16* Wob = (__bf16*)(ws + 83886080);      // 33.55 MB
  __bf16* Qb  = (__bf16*)(ws + 117440512);     // 33.55 MB  [B,32,S,D]
  __bf16* Kb  = (__bf16*)(ws + 150994944);     //  8.39 MB  [B,8,S,D]
  __bf16* Vtb = (__bf16*)(ws + 159383552);     //  8.39 MB  [B,8,D,S]
  __bf16* Ab  = (__bf16*)(ws + 167772160);     // 33.55 MB  attn out [4096][4096]
  if (ws_size < 201326592u) return;

  const int M = B_DIM * S_DIM;  // 4096

  f2bf_kernel<<<16384, 256, 0, stream>>>(hs, Xb, 16777216);
  f2bf_kernel<<<16384, 256, 0, stream>>>(wq, Wqb, 16777216);
  f2bf_kernel<<<4096, 256, 0, stream>>>(wk, Wkb, 4194304);
  f2bf_kernel<<<4096, 256, 0, stream>>>(wv, Wvb, 4194304);
  f2bf_kernel<<<16384, 256, 0, stream>>>(wo, Wob, 16777216);

  gemm_bt<0><<<dim3(32, 32), 256, 0, stream>>>(Xb, Wqb, Qb, M, 4096, 4096);
  gemm_bt<1><<<dim3(8, 32), 256, 0, stream>>>(Xb, Wkb, Kb, M, 1024, 4096);
  gemm_bt<2><<<dim3(8, 32), 256, 0, stream>>>(Xb, Wvb, Vtb, M, 1024, 4096);

  rope_kernel<<<32768, 256, 0, stream>>>(Qb, pos, 5);   // B*32*2048*64 / 256
  rope_kernel<<<8192, 256, 0, stream>>>(Kb, pos, 3);    // B*8*2048*64 / 256

  attn_kernel<<<dim3(8, 32, 2), 512, 0, stream>>>(Qb, Kb, Vtb, Ab);

  gemm_bt<3><<<dim3(32, 32), 256, 0, stream>>>(Ab, Wob, d_out, M, 4096, 4096);
}

// Round 3
// 875.418 us; speedup vs baseline: 1.4574x; 1.1958x over previous
//
#include <hip/hip_runtime.h>

typedef __attribute__((ext_vector_type(8))) __bf16 bf16x8;
typedef __attribute__((ext_vector_type(4))) __bf16 bf16x4;
typedef __attribute__((ext_vector_type(4))) float floatx4;

#define B_DIM 2
#define S_DIM 2048
#define NH    32
#define NKV   8
#define HD    128
#define HID   4096

// ---------------------------------------------------------------- helpers
__device__ __forceinline__ void gload_lds16(const void* gsrc, void* ldst) {
  __builtin_amdgcn_global_load_lds(
      (__attribute__((address_space(1))) unsigned int*)(void*)gsrc,
      (__attribute__((address_space(3))) unsigned int*)ldst, 16, 0, 0);
}

// ---------------------------------------------------------------- fp32 -> bf16
__global__ void f2bf_kernel(const float* __restrict__ in, __bf16* __restrict__ out, int n) {
  int i = (blockIdx.x * 256 + threadIdx.x) * 4;
  if (i >= n) return;
  float4 v = *(const float4*)(in + i);
  bf16x4 o;
  o.x = (__bf16)v.x; o.y = (__bf16)v.y; o.z = (__bf16)v.z; o.w = (__bf16)v.w;
  *(bf16x4*)(out + i) = o;
}

// ---------------------------------------------------------------- GEMM C = A * B^T
// A [M][K] bf16 row-major, Bw [N][K] bf16 row-major.
// 128x128 tile, BK=32, double-buffered LDS + counted vmcnt prefetch pipeline.
// LDS unit XOR-swizzle (u ^= row&3) applied on BOTH the pre-swizzled global
// source (global_load_lds writes linearly) and the fragment read side.
// MODE 0: store bf16 permuted to Q layout [B,32,S,D]
// MODE 1: store bf16 permuted to K layout [B,8,S,D]
// MODE 2: store bf16 permuted to Vt layout [B,8,D,S]
// MODE 3: store fp32 plain row-major [M][N]
__device__ __forceinline__ void gemm_stage(const __bf16* __restrict__ Ag,
                                           const __bf16* __restrict__ Bg,
                                           char* As, char* Bs, int K, int k0, int tid) {
#pragma unroll
  for (int i = 0; i < 2; i++) {
    int slot = i * 256 + tid;                  // 128 rows x 4 units (16 B)
    int row = slot >> 2;
    int u = (slot & 3) ^ (row & 3);            // inverse-swizzled source unit
    gload_lds16(Ag + (size_t)row * K + k0 + u * 8, As + slot * 16);
  }
#pragma unroll
  for (int i = 0; i < 2; i++) {
    int slot = i * 256 + tid;
    int row = slot >> 2;
    int u = (slot & 3) ^ (row & 3);
    gload_lds16(Bg + (size_t)row * K + k0 + u * 8, Bs + slot * 16);
  }
}

template <int MODE>
__global__ __launch_bounds__(256)
void gemm_bt(const __bf16* __restrict__ A, const __bf16* __restrict__ Bw,
             void* __restrict__ Cout, int M, int N, int K) {
  __shared__ uint4 smem4[2048];            // 32 KB: 2 x (As 8K + Bs 8K)
  char* smem = (char*)smem4;
  const int tid = threadIdx.x;
  const int lane = tid & 63, wave = tid >> 6;
  const int quad = lane >> 4, l16 = lane & 15;
  const int bm0 = blockIdx.y * 128, bn0 = blockIdx.x * 128;
  const __bf16* Ag = A + (size_t)bm0 * K;
  const __bf16* Bg = Bw + (size_t)bn0 * K;
  const int wm = (wave >> 1) * 64, wn = (wave & 1) * 64;

  floatx4 acc[4][4] = {};

  // prologue: stage K-tile 0 into buffer 0
  gemm_stage(Ag, Bg, smem, smem + 8192, K, 0, tid);

  const int nkt = K >> 5;
  for (int kt = 0; kt < nkt; kt++) {
    char* As = smem + (kt & 1) * 16384;
    char* Bs = As + 8192;

    if (kt + 1 < nkt) {
      char* An = smem + ((kt + 1) & 1) * 16384;
      gemm_stage(Ag, Bg, An, An + 8192, K, (kt + 1) << 5, tid);
      asm volatile("s_waitcnt vmcnt(4)" ::: "memory");   // current tile landed
    } else {
      asm volatile("s_waitcnt vmcnt(0)" ::: "memory");
    }
    __builtin_amdgcn_s_barrier();
    asm volatile("" ::: "memory");

    bf16x8 af[4], bfr[4];
#pragma unroll
    for (int i = 0; i < 4; i++) {
      int row = wm + i * 16 + l16;
      af[i] = *(const bf16x8*)(As + row * 64 + ((quad ^ (row & 3)) << 4));
    }
#pragma unroll
    for (int i = 0; i < 4; i++) {
      int row = wn + i * 16 + l16;
      bfr[i] = *(const bf16x8*)(Bs + row * 64 + ((quad ^ (row & 3)) << 4));
    }
#pragma unroll
    for (int mi = 0; mi < 4; mi++)
#pragma unroll
      for (int ni = 0; ni < 4; ni++)
        acc[mi][ni] = __builtin_amdgcn_mfma_f32_16x16x32_bf16(af[mi], bfr[ni], acc[mi][ni], 0, 0, 0);

    asm volatile("s_waitcnt lgkmcnt(0)" ::: "memory");   // frag reads complete
    __builtin_amdgcn_s_barrier();                        // buffer free for prefetch
    asm volatile("" ::: "memory");
  }

#pragma unroll
  for (int mi = 0; mi < 4; mi++)
#pragma unroll
    for (int ni = 0; ni < 4; ni++)
#pragma unroll
      for (int r = 0; r < 4; r++) {
        int row = bm0 + wm + mi * 16 + quad * 4 + r;   // m index (= b*2048+s)
        int col = bn0 + wn + ni * 16 + l16;            // n index
        float v = acc[mi][ni][r];
        if (MODE == 3) {
          ((float*)Cout)[(size_t)row * N + col] = v;
        } else {
          int b = row >> 11, s = row & 2047;
          int h = col >> 7, d = col & 127;
          size_t idx;
          if (MODE == 0)      idx = ((size_t)(b * NH + h) * S_DIM + s) * HD + d;
          else if (MODE == 1) idx = ((size_t)(b * NKV + h) * S_DIM + s) * HD + d;
          else                idx = ((size_t)(b * NKV + h) * HD + d) * S_DIM + s;
          ((__bf16*)Cout)[idx] = (__bf16)v;
        }
      }
}

// ---------------------------------------------------------------- RoPE (in place)
// x layout [B, nh, S, D]; pairs (j, j+64) rotated. lognh = log2(nh).
__global__ void rope_kernel(__bf16* __restrict__ x, const int* __restrict__ pos, int lognh) {
  int t = blockIdx.x * 256 + threadIdx.x;
  int j = t & 63;
  int s = (t >> 6) & (S_DIM - 1);
  int bh = t >> 17;
  int b = bh >> lognh;
  float p = (float)pos[b * S_DIM + s];
  float invf = exp2f((float)j * (-13.2877123795494f / 64.0f));
  float ang = p * invf;
  float sn, cs;
  sincosf(ang, &sn, &cs);
  size_t base = ((size_t)bh * S_DIM + s) * HD;
  float x1 = (float)x[base + j];
  float x2 = (float)x[base + j + 64];
  x[base + j]      = (__bf16)(x1 * cs - x2 * sn);
  x[base + j + 64] = (__bf16)(x2 * cs + x1 * sn);
}

// ---------------------------------------------------------------- flash attention
// Q [B,32,S,D], K [B,8,S,D], Vt [B,8,D,S] bf16 -> O [B,S,32*128] bf16.
// Block: 512 thr (8 waves), Q-tile 128 (16 q-rows/wave), K-tile 64, causal.
// Each block processes TWO complementary Q-tiles (qt, 15-qt) -> every block
// does exactly 34 K-tiles: perfect static balance, grid = 512 = 2 blocks/CU
// fully resident (no dispatch rounds).
// Q held in registers. K/V double-buffered in LDS, staged async via
// global_load_lds (linear LDS dest, pre-swizzled global source), counted vmcnt.
// LDS 80 KB: K dbuf 2x16K (XOR-15 swz) | V dbuf 2x16K (XOR-7) | Ps 16K (XOR-7)
__device__ __forceinline__ void stage_kv(const __bf16* __restrict__ Kg,
                                         const __bf16* __restrict__ Vg,
                                         char* Kb, char* Vb, int k0, int tid) {
#pragma unroll
  for (int i = 0; i < 2; i++) {
    int slot = i * 512 + tid;                       // 64 rows x 16 units
    int row = slot >> 4;
    int u = (slot & 15) ^ (row & 15);               // inverse-swizzled source
    gload_lds16(Kg + (size_t)(k0 + row) * HD + u * 8, Kb + slot * 16);
  }
#pragma unroll
  for (int i = 0; i < 2; i++) {
    int slot = i * 512 + tid;                       // 128 rows x 8 units
    int row = slot >> 3;
    int u = (slot & 7) ^ (row & 7);
    gload_lds16(Vg + (size_t)row * S_DIM + k0 + u * 8, Vb + slot * 16);
  }
}

__global__ __launch_bounds__(512, 4)
void attn_kernel(const __bf16* __restrict__ Q, const __bf16* __restrict__ K,
                 const __bf16* __restrict__ Vt, __bf16* __restrict__ O) {
  __shared__ uint4 smem4[5120];            // 81920 B
  char* smem = (char*)smem4;
  char* Ps = smem + 65536;                 // 128 rows x 128 B
  const int tid = threadIdx.x;
  const int lane = tid & 63, wave = tid >> 6;
  const int quad = lane >> 4, l16 = lane & 15;
  const int h = blockIdx.y, b = blockIdx.z;
  const int kvh = h >> 2;
  const __bf16* Kg = K + (size_t)(b * NKV + kvh) * S_DIM * HD;
  const __bf16* Vg = Vt + (size_t)(b * NKV + kvh) * HD * S_DIM;
  const float scale = 0.08838834764831845f;   // 1/sqrt(128)

  for (int pass = 0; pass < 2; ++pass) {
    const int qt = pass ? (15 - (int)blockIdx.x) : (int)blockIdx.x;
    const int q0 = qt * 128;
    const __bf16* Qg = Q + ((size_t)(b * NH + h) * S_DIM + q0) * HD;
    const int nkt = qt * 2 + 2;

    // Q fragments in registers (wave owns 16 q-rows)
    bf16x8 qf[4];
#pragma unroll
    for (int ks = 0; ks < 4; ks++)
      qf[ks] = *(const bf16x8*)(Qg + (wave * 16 + l16) * HD + (ks * 4 + quad) * 8);

    floatx4 oacc[8] = {};
    float mrow[4] = {-1e30f, -1e30f, -1e30f, -1e30f};
    float lrow[4] = {0.f, 0.f, 0.f, 0.f};

    // prologue: stage tile 0 into buffer 0
    stage_kv(Kg, Vg, smem, smem + 32768, 0, tid);

    for (int kt = 0; kt < nkt; kt++) {
      char* Kc = smem + (kt & 1) * 16384;
      char* Vc = smem + 32768 + (kt & 1) * 16384;
      const int k0 = kt * 64;

      if (kt + 1 < nkt) {
        // issue next tile's 4 DMA loads/thread into the other buffer, then
        // wait only for the current tile's 4 (counted vmcnt)
        stage_kv(Kg, Vg, smem + ((kt + 1) & 1) * 16384,
                 smem + 32768 + ((kt + 1) & 1) * 16384, k0 + 64, tid);
        asm volatile("s_waitcnt vmcnt(4)" ::: "memory");
      } else {
        asm volatile("s_waitcnt vmcnt(0)" ::: "memory");
      }
      __builtin_amdgcn_s_barrier();            // tile kt data visible to all waves
      asm volatile("" ::: "memory");

      // ---- S = Q K^T
      floatx4 sacc[4] = {};
#pragma unroll
      for (int ks = 0; ks < 4; ks++) {
        bf16x8 bk[4];
#pragma unroll
        for (int n = 0; n < 4; n++) {
          int row = n * 16 + l16;
          bk[n] = *(const bf16x8*)(Kc + row * 256 + (((ks * 4 + quad) ^ (row & 15)) << 4));
        }
#pragma unroll
        for (int n = 0; n < 4; n++)
          sacc[n] = __builtin_amdgcn_mfma_f32_16x16x32_bf16(qf[ks], bk[n], sacc[n], 0, 0, 0);
      }

      // ---- online softmax (rows wave-private)
      const bool maskt = (kt >= nkt - 2);      // diagonal-crossing tiles
      float pm[4][4];
      float rmax[4] = {-3e30f, -3e30f, -3e30f, -3e30f};
#pragma unroll
      for (int n = 0; n < 4; n++)
#pragma unroll
        for (int r = 0; r < 4; r++) {
          float sv = sacc[n][r] * scale;
          if (maskt) {
            int qrow = q0 + wave * 16 + quad * 4 + r;
            int kcol = k0 + n * 16 + l16;
            if (kcol > qrow) sv = -1e30f;
          }
          pm[n][r] = sv;
          rmax[r] = fmaxf(rmax[r], sv);
        }
#pragma unroll
      for (int r = 0; r < 4; r++) {
        float v = rmax[r];
        v = fmaxf(v, __shfl_xor(v, 1));
        v = fmaxf(v, __shfl_xor(v, 2));
        v = fmaxf(v, __shfl_xor(v, 4));
        v = fmaxf(v, __shfl_xor(v, 8));
        float nm = fmaxf(mrow[r], v);
        float al = __expf(mrow[r] - nm);
        mrow[r] = nm;
        float rs = 0.f;
#pragma unroll
        for (int n = 0; n < 4; n++) {
          float p = __expf(pm[n][r] - nm);
          pm[n][r] = p;
          rs += p;
        }
        rs += __shfl_xor(rs, 1);
        rs += __shfl_xor(rs, 2);
        rs += __shfl_xor(rs, 4);
        rs += __shfl_xor(rs, 8);
        lrow[r] = lrow[r] * al + rs;
#pragma unroll
        for (int n = 0; n < 8; n++) oacc[n][r] *= al;
      }
      // write P (bf16) to LDS — wave-private rows, no barrier needed
#pragma unroll
      for (int n = 0; n < 4; n++)
#pragma unroll
        for (int r = 0; r < 4; r++) {
          int row = wave * 16 + quad * 4 + r;
          int col = n * 16 + l16;
          *(__bf16*)(Ps + row * 128 + (((col >> 3) ^ (row & 7)) << 4) + (col & 7) * 2) =
              (__bf16)pm[n][r];
        }
      asm volatile("s_waitcnt lgkmcnt(0)" ::: "memory");   // P writes landed

      // ---- O += P V
#pragma unroll
      for (int ks = 0; ks < 2; ks++) {
        int prow = wave * 16 + l16;
        bf16x8 ap = *(const bf16x8*)(Ps + prow * 128 + (((ks * 4 + quad) ^ (prow & 7)) << 4));
#pragma unroll
        for (int n = 0; n < 8; n++) {
          int vrow = n * 16 + l16;
          bf16x8 bv = *(const bf16x8*)(Vc + vrow * 128 + (((ks * 4 + quad) ^ (vrow & 7)) << 4));
          oacc[n] = __builtin_amdgcn_mfma_f32_16x16x32_bf16(ap, bv, oacc[n], 0, 0, 0);
        }
      }

      asm volatile("" ::: "memory");
      __builtin_amdgcn_s_barrier();            // buffers free for next prefetch
      asm volatile("" ::: "memory");
    }

    // epilogue: O /= l, store to [B,S,H*D]
#pragma unroll
    for (int n = 0; n < 8; n++)
#pragma unroll
      for (int r = 0; r < 4; r++) {
        int row = wave * 16 + quad * 4 + r;
        int col = n * 16 + l16;
        float v = oacc[n][r] / lrow[r];
        O[(size_t)(b * S_DIM + q0 + row) * HID + h * HD + col] = (__bf16)v;
      }
  }
}

// ---------------------------------------------------------------- launch
extern "C" void kernel_launch(void* const* d_in, const int* in_sizes, int n_in,
                              void* d_out, int out_size, void* d_ws, size_t ws_size,
                              hipStream_t stream) {
  const float* hs = (const float*)d_in[0];
  const float* wq = (const float*)d_in[1];
  const float* wk = (const float*)d_in[2];
  const float* wv = (const float*)d_in[3];
  const float* wo = (const float*)d_in[4];
  // d_in[5] = attention_mask (pure causal; implemented directly)
  const int* pos = (const int*)d_in[6];

  char* ws = (char*)d_ws;
  __bf16* Xb  = (__bf16*)(ws);                 // 33.55 MB  [4096][4096]
  __bf16* Wqb = (__bf16*)(ws + 33554432);      // 33.55 MB
  __bf16* Wkb = (__bf16*)(ws + 67108864);      //  8.39 MB
  __bf16* Wvb = (__bf16*)(ws + 75497472);      //  8.39 MB
  __bf16* Wob = (__bf16*)(ws + 83886080);      // 33.55 MB
  __bf16* Qb  = (__bf16*)(ws + 117440512);     // 33.55 MB  [B,32,S,D]
  __bf16* Kb  = (__bf16*)(ws + 150994944);     //  8.39 MB  [B,8,S,D]
  __bf16* Vtb = (__bf16*)(ws + 159383552);     //  8.39 MB  [B,8,D,S]
  __bf16* Ab  = (__bf16*)(ws + 167772160);     // 33.55 MB  attn out [4096][4096]
  if (ws_size < 201326592u) return;

  const int M = B_DIM * S_DIM;  // 4096

  f2bf_kernel<<<16384, 256, 0, stream>>>(hs, Xb, 16777216);
  f2bf_kernel<<<16384, 256, 0, stream>>>(wq, Wqb, 16777216);
  f2bf_kernel<<<4096, 256, 0, stream>>>(wk, Wkb, 4194304);
  f2bf_kernel<<<4096, 256, 0, stream>>>(wv, Wvb, 4194304);
  f2bf_kernel<<<16384, 256, 0, stream>>>(wo, Wob, 16777216);

  gemm_bt<0><<<dim3(32, 32), 256, 0, stream>>>(Xb, Wqb, Qb, M, 4096, 4096);
  gemm_bt<1><<<dim3(8, 32), 256, 0, stream>>>(Xb, Wkb, Kb, M, 1024, 4096);
  gemm_bt<2><<<dim3(8, 32), 256, 0, stream>>>(Xb, Wvb, Vtb, M, 1024, 4096);

  rope_kernel<<<32768, 256, 0, stream>>>(Qb, pos, 5);   // B*32*2048*64 / 256
  rope_kernel<<<8192, 256, 0, stream>>>(Kb, pos, 3);    // B*8*2048*64 / 256

  attn_kernel<<<dim3(8, 32, 2), 512, 0, stream>>>(Qb, Kb, Vtb, Ab);

  gemm_bt<3><<<dim3(32, 32), 256, 0, stream>>>(Ab, Wob, d_out, M, 4096, 4096);
}